// Round 7
// baseline (29.746 us; speedup 1.0000x reference)
//
#include <hip/hip_runtime.h>

#define NB 65536
#define ND 8
#define NE 16
#define NH 80
#define NF 9
#define NV 100000
#define NIN 160
#define WND 512   // samples per window; block = (window, domain)

typedef __attribute__((ext_vector_type(8))) short short8;    // 8 bf16 (4 VGPRs)
typedef __attribute__((ext_vector_type(4))) float float4v;   // MFMA acc

// ws layout in 4-byte units (weights only — no per-sample metadata at all)
#define WS_W1BF   0        // bf16 fused W1, [d][n][k]: 8*80*160 ushort = 51200 u32
#define WS_B1F    51200    // 640 f32 [d][h]
#define WS_W2F    51840    // 640 f32 [d][h]
#define WS_B2F    52480    // 8 f32

__device__ inline unsigned short f2bf(float x) {   // RNE f32->bf16
  unsigned int u = __float_as_uint(x);
  return (unsigned short)((u + 0x7fffu + ((u >> 16) & 1u)) >> 16);
}

// k_fuse: star-merge the weights once. Tiny (51200 u32 outputs).
__global__ void k_fuse(const float* __restrict__ sw1, const float* __restrict__ dw1,
                       const float* __restrict__ sb1, const float* __restrict__ db1,
                       const float* __restrict__ sw2, const float* __restrict__ dw2,
                       const float* __restrict__ sb2, const float* __restrict__ db2,
                       unsigned int* __restrict__ w1bf, float* __restrict__ wsf) {
  int t = blockIdx.x * 256 + threadIdx.x;
  if (t < ND * NH * (NIN / 2)) {          // one uint = 2 consecutive k of W1bf[d][n][k]
    int d = t / (NH * (NIN / 2));
    int r = t % (NH * (NIN / 2));
    int n = r / (NIN / 2);
    int k0 = (r % (NIN / 2)) * 2;
    float a = sw1[k0 * NH + n] * dw1[d * NIN * NH + k0 * NH + n];
    float b = sw1[(k0 + 1) * NH + n] * dw1[d * NIN * NH + (k0 + 1) * NH + n];
    w1bf[t] = (unsigned)f2bf(a) | ((unsigned)f2bf(b) << 16);
  }
  if (t < ND * NH) {
    wsf[WS_B1F + t] = sb1[t % NH] + db1[t];
    wsf[WS_W2F + t] = sw2[t % NH] * dw2[t];
  }
  if (t < ND) wsf[WS_B2F + t] = sb2[0] + db2[t];
}

// k_main: block = (512-sample window, domain). Local ballot-compact replaces
// all global bucketing metadata: pid (coalesced) -> ballot ranks -> sid[] in
// LDS -> feats -> embedding gather -> relu/bf16 -> sA -> MFMA 16x16x32 ->
// fused layer-2 epilogue. Zero atomics, zero workspace metadata.
__global__ __launch_bounds__(256) void k_main(
    const int* __restrict__ pid, const int* __restrict__ feats,
    const float* __restrict__ emb_pid, const float* __restrict__ emb_feats,
    const float* __restrict__ dl_w, const float* __restrict__ dl_b,
    const unsigned int* __restrict__ w1bf, const float* __restrict__ wsf,
    float* __restrict__ out) {
  const int d = blockIdx.x & 7;
  const int wnd = blockIdx.x >> 3;
  const int t = threadIdx.x, wave = t >> 6, lane = t & 63;

  __shared__ unsigned short sA[64][168];   // 21504 B
  __shared__ unsigned short sB[80][168];   // 26880 B
  __shared__ int sid[WND];                 // compacted sample ids
  __shared__ int cnt[2][4];

  // 1) issue pid window loads (head of the dependent chain)
  const int b0 = wnd * WND + t;
  const int b1 = b0 + 256;
  const int p0 = pid[b0];
  const int p1 = pid[b1];

  // 2) stage fused W1 (bf16 [n][k]) into LDS — independent stream, overlaps
  const unsigned int* __restrict__ wb = w1bf + d * (NH * (NIN / 2));
  for (int i = t; i < NH * (NIN / 2); i += 256) {
    int n = i / (NIN / 2), kp = i % (NIN / 2);
    ((unsigned int*)&sB[n][0])[kp] = wb[i];
  }

  const float dlb = dl_b[0];
  if (d == 0) {  // padding rows: e_pid row is zeros -> logits = dl_b exactly
    if (p0 == 0) out[b0] = dlb;
    if (p1 == 0) out[b1] = dlb;
  }

  // 3) ballot-rank compaction, two passes (t and t+256)
  unsigned long long m0 = __ballot(p0 == d + 1);
  unsigned long long m1 = __ballot(p1 == d + 1);
  if (lane == 0) { cnt[0][wave] = (int)__popcll(m0); cnt[1][wave] = (int)__popcll(m1); }
  const int r0 = (int)__popcll(m0 & ((1ull << lane) - 1ull));
  const int r1 = (int)__popcll(m1 & ((1ull << lane) - 1ull));

  // bucket-uniform hoists (register-only, independent of the chain)
  float dlacc = dlb;
  unsigned int ep[8];
  {
    const float* __restrict__ row = emb_pid + (d + 1) * NE;
#pragma unroll
    for (int i = 0; i < NE; i += 2) {
      float x0 = fmaxf(row[i], 0.f), x1 = fmaxf(row[i + 1], 0.f);
      dlacc = fmaf(x0, dl_w[i], dlacc);
      dlacc = fmaf(x1, dl_w[i + 1], dlacc);
      ep[i >> 1] = (unsigned)f2bf(x0) | ((unsigned)f2bf(x1) << 16);
    }
  }
  const float b2 = wsf[WS_B2F + d];
  float b1l[5], w2l[5];
#pragma unroll
  for (int nt = 0; nt < 5; ++nt) {
    b1l[nt] = wsf[WS_B1F + d * NH + nt * 16 + (lane & 15)];
    w2l[nt] = wsf[WS_W2F + d * NH + nt * 16 + (lane & 15)];
  }

  __syncthreads();   // cnt visible
  int base0 = 0, base1 = 0;
#pragma unroll
  for (int w = 0; w < 4; ++w) {
    if (w < wave) { base0 += cnt[0][w]; base1 += cnt[1][w]; }
  }
  const int tot0 = cnt[0][0] + cnt[0][1] + cnt[0][2] + cnt[0][3];
  const int c = tot0 + cnt[1][0] + cnt[1][1] + cnt[1][2] + cnt[1][3];
  if (p0 == d + 1) sid[base0 + r0] = b0;
  if (p1 == d + 1) sid[tot0 + base1 + r1] = b1;
  __syncthreads();   // sid ready

  for (int g0 = 0; g0 < c; g0 += 64) {
    // ---- stage A: 4 threads per sample ----
    const int s = t >> 2, q = t & 3;
    const int ss = g0 + s;
    const int bb = sid[ss < c ? ss : 0];
    int idx[NF];
#pragma unroll
    for (int f = 0; f < NF; ++f) idx[f] = feats[bb * NF + f];
    float4 vv[NF];
#pragma unroll
    for (int f = 0; f < NF; ++f)
      vv[f] = ((const float4*)(emb_feats + ((size_t)f * (NV + 1) + (size_t)idx[f]) * NE))[q];
    if (q < 2) {  // e_pid columns 0..15 (bucket-uniform row)
      unsigned int* dst = (unsigned int*)&sA[s][0];
#pragma unroll
      for (int j = 0; j < 4; ++j) dst[q * 4 + j] = ep[q * 4 + j];
    }
#pragma unroll
    for (int f = 0; f < NF; ++f) {
      unsigned int pk0 = (unsigned)f2bf(fmaxf(vv[f].x, 0.f)) |
                         ((unsigned)f2bf(fmaxf(vv[f].y, 0.f)) << 16);
      unsigned int pk1 = (unsigned)f2bf(fmaxf(vv[f].z, 0.f)) |
                         ((unsigned)f2bf(fmaxf(vv[f].w, 0.f)) << 16);
      unsigned int* dst = (unsigned int*)&sA[s][16 + f * 16];
      dst[q * 2] = pk0;
      dst[q * 2 + 1] = pk1;
    }
    __syncthreads();

    // ---- MFMA: A lane l -> row l&15, k=(l>>4)*8+e ; B lane l -> col l&15 ----
    float4v acc[5];
#pragma unroll
    for (int nt = 0; nt < 5; ++nt)
      acc[nt] = (float4v){b1l[nt], b1l[nt], b1l[nt], b1l[nt]};
    const int arow = wave * 16 + (lane & 15);
    const int koff = (lane >> 4) * 8;
#pragma unroll
    for (int ks = 0; ks < 5; ++ks) {
      short8 af = *(const short8*)&sA[arow][ks * 32 + koff];
#pragma unroll
      for (int nt = 0; nt < 5; ++nt) {
        short8 bf = *(const short8*)&sB[nt * 16 + (lane & 15)][ks * 32 + koff];
        acc[nt] = __builtin_amdgcn_mfma_f32_16x16x32_bf16(af, bf, acc[nt], 0, 0, 0);
      }
    }

    // ---- layer 2: relu(h) . w2, reduce across the 16-lane n-groups ----
    float pr[4];
#pragma unroll
    for (int r = 0; r < 4; ++r) {
      float a2 = 0.f;
#pragma unroll
      for (int nt = 0; nt < 5; ++nt) a2 = fmaf(fmaxf(acc[nt][r], 0.f), w2l[nt], a2);
      pr[r] = a2;
    }
#pragma unroll
    for (int r = 0; r < 4; ++r) {
      pr[r] += __shfl_xor(pr[r], 1);
      pr[r] += __shfl_xor(pr[r], 2);
      pr[r] += __shfl_xor(pr[r], 4);
      pr[r] += __shfl_xor(pr[r], 8);
    }
    if ((lane & 15) == 0) {
      int srow = wave * 16 + (lane >> 4) * 4;
#pragma unroll
      for (int r = 0; r < 4; ++r) {
        int kk = g0 + srow + r;
        if (kk < c) out[sid[kk]] = pr[r] + b2 + dlacc;
      }
    }
    __syncthreads();   // before next group overwrites sA
  }
}

extern "C" void kernel_launch(void* const* d_in, const int* in_sizes, int n_in,
                              void* d_out, int out_size, void* d_ws, size_t ws_size,
                              hipStream_t stream) {
  const int*   pid      = (const int*)d_in[0];
  const int*   feats    = (const int*)d_in[1];
  const float* emb_pid  = (const float*)d_in[2];
  const float* emb_f    = (const float*)d_in[3];
  const float* sw1      = (const float*)d_in[4];
  const float* dw1      = (const float*)d_in[5];
  const float* sb1      = (const float*)d_in[6];
  const float* db1      = (const float*)d_in[7];
  const float* sw2      = (const float*)d_in[8];
  const float* dw2      = (const float*)d_in[9];
  const float* sb2      = (const float*)d_in[10];
  const float* db2      = (const float*)d_in[11];
  const float* dl_w     = (const float*)d_in[12];
  const float* dl_b     = (const float*)d_in[13];
  float* out = (float*)d_out;
  float* wsf = (float*)d_ws;
  unsigned int* w1bf = (unsigned int*)d_ws;

  k_fuse<<<(ND * NH * (NIN / 2) + 255) / 256, 256, 0, stream>>>(
      sw1, dw1, sb1, db1, sw2, dw2, sb2, db2, w1bf, wsf);
  k_main<<<(NB / WND) * ND, 256, 0, stream>>>(pid, feats, emb_pid, emb_f,
                                              dl_w, dl_b, w1bf, wsf, out);
}